// Round 6
// baseline (351.761 us; speedup 1.0000x reference)
//
#include <hip/hip_runtime.h>

typedef unsigned int   u32;
typedef unsigned short u16;
typedef __bf16 bf16x8 __attribute__((ext_vector_type(8)));
typedef float  f32x4  __attribute__((ext_vector_type(4)));

__device__ __forceinline__ u16 f2bf(float f) {
    u32 u = __builtin_bit_cast(u32, f);
    u += 0x7FFFu + ((u >> 16) & 1u);
    return (u16)(u >> 16);
}
__device__ __forceinline__ u32 pk2bf(float a, float b) {
    return (u32)f2bf(a) | ((u32)f2bf(b) << 16);
}
__device__ __forceinline__ bf16x8 ldfrag(const u16* p) {
    return __builtin_bit_cast(bf16x8, *reinterpret_cast<const uint4*>(p));
}

// bank-conflict swizzle on the 16B-chunk index (0..63): fold bits[5:3] into [2:0].
__device__ __forceinline__ u32 swz(u32 i) { return i ^ ((i >> 3) & 7u); }

// ---------------------------------------------------------------------------
// Fused Swin branch: LN -> QKV -> windowed MHA -> proj -> +residual
// One WG per 8x8 window; 384 threads = 6 waves = 6 heads.
// LDS (u16):
//   [0,12288)      yln: 24 frag blocks (mi*6+ks)*512 + swz(pos)*8 + j.
//                  Phase 3: wave w's own blocks {s*6+w} = scratch for
//                  k -> V^T -> attn_out (serial, wave-local, DS in-order).
//   [12288,24576)  qreg: per-head q A-frags; P staging reuses it after QK^T.
// k and v cross the QKV barrier packed in registers (kpk/vpk, 16 u32).
// LDS ~51KB/WG: 2 WGs fit the ~128KB schedulable pool (R2/R3/R5 evidence);
// __launch_bounds__(384,3) caps regs at 170 (need ~148 incl AGPR).
// ---------------------------------------------------------------------------
template<int SHIFT>
__global__ __launch_bounds__(384, 3) void swin_branch(
    const float* __restrict__ xin, float* __restrict__ xout,
    const float* __restrict__ ln_g, const float* __restrict__ ln_b,
    const u16*   __restrict__ wqkv_t,  // [576][192] bf16 (pre-transposed)
    const float* __restrict__ qkv_b,   // [576]
    const u16*   __restrict__ wproj_t, // [192][192] bf16 (pre-transposed)
    const float* __restrict__ proj_b)  // [192]
{
    __shared__ __align__(16) u16 smem[24576];
    __shared__ float red1[6][64];
    __shared__ float red2[6][64];
    constexpr u32 QOFF = 12288;

    const int tid  = threadIdx.x;
    const int wid  = tid >> 6;      // wave == head
    const int lane = tid & 63;
    const int lr   = lane & 15;
    const int lg   = lane >> 4;
    const u32 lsw  = swz((u32)lane);   // read-side chunk index

    const int Wid = blockIdx.x;     // b*256 + wy*16 + wx
    const int b   = Wid >> 8;
    const int wy  = (Wid >> 4) & 15;
    const int wx  = Wid & 15;

    // ---- Phase 1: gather window (rolled), LayerNorm -> yln (A-frag layout) ----
    {
        const int ty = lane >> 3, tx = lane & 7;
        const int shy = (wy*8 + ty + SHIFT) & 127;
        const int shx = (wx*8 + tx + SHIFT) & 127;
        const float* xp = xin + ((size_t)((b*128 + shy)*128 + shx))*192 + wid*32;
        float xv[32];
        float s1 = 0.f, s2 = 0.f;
        #pragma unroll
        for (int j = 0; j < 8; ++j) {
            float4 v = reinterpret_cast<const float4*>(xp)[j];
            xv[j*4+0]=v.x; xv[j*4+1]=v.y; xv[j*4+2]=v.z; xv[j*4+3]=v.w;
            s1 += v.x+v.y+v.z+v.w;
            s2 += v.x*v.x + v.y*v.y + v.z*v.z + v.w*v.w;
        }
        red1[wid][lane] = s1; red2[wid][lane] = s2;
        __syncthreads();
        // every thread reduces its token's 6 partials (redundant across waves,
        // but saves a barrier + an LDS roundtrip)
        float a1 = 0.f, a2 = 0.f;
        #pragma unroll
        for (int w = 0; w < 6; ++w) { a1 += red1[w][lane]; a2 += red2[w][lane]; }
        const float mu = a1 * (1.f/192.f);
        const float rs = rsqrtf(a2 * (1.f/192.f) - mu*mu + 1e-5f);
        const float* gp = ln_g + wid*32;
        const float* bp = ln_b + wid*32;
        const u32 yblk = (u32)((lg*6 + wid)*512);
        #pragma unroll
        for (int cc8 = 0; cc8 < 4; ++cc8) {
            u32 pk[4];
            #pragma unroll
            for (int q = 0; q < 4; ++q) {
                int j = cc8*8 + q*2;
                float y0 = (xv[j]   - mu)*rs*gp[j]   + bp[j];
                float y1 = (xv[j+1] - mu)*rs*gp[j+1] + bp[j+1];
                pk[q] = pk2bf(y0, y1);
            }
            *reinterpret_cast<uint4*>(&smem[yblk + swz((u32)(lr + 16*cc8))*8]) =
                make_uint4(pk[0],pk[1],pk[2],pk[3]);
        }
    }
    __syncthreads();

    // ---- Phase 2: QKV GEMM, two passes to cap accumulator liveness ----
    uint2 kpk[4][2];     // k packed bf16 (crosses barrier in regs)
    uint2 vpk[4][2];     // v packed bf16 (crosses barrier in regs)
    {
        // pass 1: q,k (16 accumulators); q -> qreg (wave-private LDS, pre-barrier)
        {
            f32x4 acc[4][4];
            #pragma unroll
            for (int mi=0; mi<4; ++mi)
                #pragma unroll
                for (int t=0; t<4; ++t) acc[mi][t] = f32x4{0.f,0.f,0.f,0.f};
            #pragma unroll
            for (int ks=0; ks<6; ++ks) {
                bf16x8 af[4];
                #pragma unroll
                for (int mi=0; mi<4; ++mi)
                    af[mi] = ldfrag(&smem[(u32)((mi*6+ks)*512) + lsw*8]);
                bf16x8 bw[4];
                #pragma unroll
                for (int t=0; t<4; ++t)
                    bw[t] = ldfrag(&wqkv_t[((t>>1)*192 + wid*32 + (t&1)*16 + lr)*192 + 32*ks + 8*lg]);
                #pragma unroll
                for (int mi=0; mi<4; ++mi)
                    #pragma unroll
                    for (int t=0; t<4; ++t)
                        acc[mi][t] = __builtin_amdgcn_mfma_f32_16x16x32_bf16(af[mi], bw[t], acc[mi][t], 0,0,0);
            }
            // q: bias+scale, scatter to qreg; k: bias, pack to regs
            #pragma unroll
            for (int t=0; t<2; ++t) {
                const float bias = qkv_b[wid*32 + t*16 + lr];
                const u32 lphi   = (u32)(16*(2*t + (lr>>3)));
                #pragma unroll
                for (int mi=0; mi<4; ++mi)
                    #pragma unroll
                    for (int rg=0; rg<4; ++rg) {
                        const u32 pos = (u32)(4*lg + rg) + lphi;
                        smem[QOFF + (u32)(wid*2048) + mi*512 + swz(pos)*8 + (lr&7)] =
                            f2bf((acc[mi][t][rg] + bias) * 0.1767766952966369f);
                    }
            }
            #pragma unroll
            for (int t2=0; t2<2; ++t2) {
                const float bias = qkv_b[192 + wid*32 + t2*16 + lr];
                #pragma unroll
                for (int mi=0; mi<4; ++mi)
                    kpk[mi][t2] = make_uint2(
                        pk2bf(acc[mi][2+t2][0] + bias, acc[mi][2+t2][1] + bias),
                        pk2bf(acc[mi][2+t2][2] + bias, acc[mi][2+t2][3] + bias));
            }
        }
        // pass 2: v (8 accumulators), pack to bf16 pairs
        {
            f32x4 vacc[4][2];
            #pragma unroll
            for (int mi=0; mi<4; ++mi)
                #pragma unroll
                for (int t=0; t<2; ++t) vacc[mi][t] = f32x4{0.f,0.f,0.f,0.f};
            #pragma unroll
            for (int ks=0; ks<6; ++ks) {
                bf16x8 af[4];
                #pragma unroll
                for (int mi=0; mi<4; ++mi)
                    af[mi] = ldfrag(&smem[(u32)((mi*6+ks)*512) + lsw*8]);
                bf16x8 bw[2];
                #pragma unroll
                for (int t=0; t<2; ++t)
                    bw[t] = ldfrag(&wqkv_t[(384 + wid*32 + t*16 + lr)*192 + 32*ks + 8*lg]);
                #pragma unroll
                for (int mi=0; mi<4; ++mi)
                    #pragma unroll
                    for (int t=0; t<2; ++t)
                        vacc[mi][t] = __builtin_amdgcn_mfma_f32_16x16x32_bf16(af[mi], bw[t], vacc[mi][t], 0,0,0);
            }
            #pragma unroll
            for (int tv=0; tv<2; ++tv) {
                const float bias = qkv_b[384 + wid*32 + tv*16 + lr];
                #pragma unroll
                for (int mi=0; mi<4; ++mi)
                    vpk[mi][tv] = make_uint2(
                        pk2bf(vacc[mi][tv][0] + bias, vacc[mi][tv][1] + bias),
                        pk2bf(vacc[mi][tv][2] + bias, vacc[mi][tv][3] + bias));
            }
        }
    }
    __syncthreads();   // yln reads done -> wave w's blocks {s*6+w} become scratch

    // ---- Phase 3: attention, fully wave-local ----
    float rsum[4][4];
    f32x4 o_[4][2];
    {
        const u32 W  = (u32)(wid*512);
        const u32 qb = QOFF + (u32)(wid*2048);
        #define BLK(s) ((u32)(s)*3072u + W)

        // k scatter (from kpk) -> scratch blocks, read B-frags
        #pragma unroll
        for (int t2=0; t2<2; ++t2) {
            const u32 lphi = (u32)(16*(2*t2 + (lr>>3)));
            #pragma unroll
            for (int mi=0; mi<4; ++mi) {
                const u32 a0 = BLK(mi) + (lr&7);
                smem[a0 + swz((u32)(4*lg+0) + lphi)*8] = (u16)(kpk[mi][t2].x);
                smem[a0 + swz((u32)(4*lg+1) + lphi)*8] = (u16)(kpk[mi][t2].x >> 16);
                smem[a0 + swz((u32)(4*lg+2) + lphi)*8] = (u16)(kpk[mi][t2].y);
                smem[a0 + swz((u32)(4*lg+3) + lphi)*8] = (u16)(kpk[mi][t2].y >> 16);
            }
        }
        bf16x8 aq[4], bk[4];
        #pragma unroll
        for (int mi=0; mi<4; ++mi) aq[mi] = ldfrag(&smem[qb + mi*512 + lsw*8]);
        #pragma unroll
        for (int ni=0; ni<4; ++ni) bk[ni] = ldfrag(&smem[BLK(ni) + lsw*8]);
        __builtin_amdgcn_sched_barrier(0);

        // V^T scatter into same scratch (k dead after bk reads; DS in-order)
        #pragma unroll
        for (int tv=0; tv<2; ++tv)
            #pragma unroll
            for (int mi=0; mi<4; ++mi) {
                const u32 pos = (u32)(lr + 16*(2*(mi&1) + (lg>>1)));
                *reinterpret_cast<uint2*>(
                    &smem[BLK(tv*2 + (mi>>1)) + swz(pos)*8 + 4*(lg&1)]) = vpk[mi][tv];
            }

        f32x4 s[4][4];
        #pragma unroll
        for (int mi=0; mi<4; ++mi)
            #pragma unroll
            for (int ni=0; ni<4; ++ni)
                s[mi][ni] = __builtin_amdgcn_mfma_f32_16x16x32_bf16(aq[mi], bk[ni],
                                f32x4{0.f,0.f,0.f,0.f}, 0,0,0);

        if constexpr (SHIFT > 0) {
            int kl[4];
            #pragma unroll
            for (int ni=0; ni<4; ++ni) {
                const int col = 16*ni + lr;
                const int hu = wy*8 + (col>>3);
                const int wu = wx*8 + (col&7);
                kl[ni] = ((hu >= 124) ? 2 : (hu >= 120 ? 1 : 0))*3
                       + ((wu >= 124) ? 2 : (wu >= 120 ? 1 : 0));
            }
            #pragma unroll
            for (int mi=0; mi<4; ++mi)
                #pragma unroll
                for (int rg=0; rg<4; ++rg) {
                    const int row = 16*mi + 4*lg + rg;
                    const int hu = wy*8 + (row>>3);
                    const int wu = wx*8 + (row&7);
                    const int rl = ((hu >= 124) ? 2 : (hu >= 120 ? 1 : 0))*3
                                 + ((wu >= 124) ? 2 : (wu >= 120 ? 1 : 0));
                    #pragma unroll
                    for (int ni=0; ni<4; ++ni)
                        if (rl != kl[ni]) s[mi][ni][rg] += -100.f;
                }
        }

        // row softmax in registers (row's 64 cols = 16 lanes x 4 ni)
        #pragma unroll
        for (int mi=0; mi<4; ++mi)
            #pragma unroll
            for (int rg=0; rg<4; ++rg) {
                float m = fmaxf(fmaxf(s[mi][0][rg], s[mi][1][rg]), fmaxf(s[mi][2][rg], s[mi][3][rg]));
                #pragma unroll
                for (int off=1; off<16; off<<=1) m = fmaxf(m, __shfl_xor(m, off, 64));
                float sm = 0.f;
                #pragma unroll
                for (int ni=0; ni<4; ++ni) {
                    float e = __expf(s[mi][ni][rg] - m);
                    s[mi][ni][rg] = e;
                    sm += e;
                }
                #pragma unroll
                for (int off=1; off<16; off<<=1) sm += __shfl_xor(sm, off, 64);
                rsum[mi][rg] = 1.0f / sm;
            }

        // P staged in two ksv halves in qreg (q dead after QK^T); frags to regs
        bf16x8 ap0[4], ap1[4];
        #pragma unroll
        for (int mi=0; mi<4; ++mi)
            #pragma unroll
            for (int ni=0; ni<2; ++ni)
                #pragma unroll
                for (int rg=0; rg<4; ++rg) {
                    const u32 pos = (u32)(4*lg + rg + 16*(2*ni + (lr>>3)));
                    smem[qb + mi*512 + swz(pos)*8 + (lr&7)] = f2bf(s[mi][ni][rg]);
                }
        #pragma unroll
        for (int mi=0; mi<4; ++mi) ap0[mi] = ldfrag(&smem[qb + mi*512 + lsw*8]);
        __builtin_amdgcn_sched_barrier(0);
        #pragma unroll
        for (int mi=0; mi<4; ++mi)
            #pragma unroll
            for (int ni=2; ni<4; ++ni)
                #pragma unroll
                for (int rg=0; rg<4; ++rg) {
                    const u32 pos = (u32)(4*lg + rg + 16*(2*(ni-2) + (lr>>3)));
                    smem[qb + mi*512 + swz(pos)*8 + (lr&7)] = f2bf(s[mi][ni][rg]);
                }
        #pragma unroll
        for (int mi=0; mi<4; ++mi) ap1[mi] = ldfrag(&smem[qb + mi*512 + lsw*8]);
        __builtin_amdgcn_sched_barrier(0);

        bf16x8 bv[2][2];
        #pragma unroll
        for (int tv=0; tv<2; ++tv)
            #pragma unroll
            for (int ksv=0; ksv<2; ++ksv)
                bv[tv][ksv] = ldfrag(&smem[BLK(tv*2+ksv) + lsw*8]);

        // PV
        #pragma unroll
        for (int mi=0; mi<4; ++mi)
            #pragma unroll
            for (int tv=0; tv<2; ++tv) {
                o_[mi][tv] = __builtin_amdgcn_mfma_f32_16x16x32_bf16(ap0[mi], bv[tv][0],
                                 f32x4{0.f,0.f,0.f,0.f}, 0,0,0);
                o_[mi][tv] = __builtin_amdgcn_mfma_f32_16x16x32_bf16(ap1[mi], bv[tv][1],
                                 o_[mi][tv], 0,0,0);
            }
        __builtin_amdgcn_sched_barrier(0);

        // normalized attn_out -> own scratch blocks (= proj A-frag blocks ks=wid)
        #pragma unroll
        for (int mi=0; mi<4; ++mi)
            #pragma unroll
            for (int tv=0; tv<2; ++tv)
                #pragma unroll
                for (int rg=0; rg<4; ++rg) {
                    const u32 pos = (u32)(4*lg + rg + 16*(2*tv + (lr>>3)));
                    smem[BLK(mi) + swz(pos)*8 + (lr&7)] = f2bf(o_[mi][tv][rg] * rsum[mi][rg]);
                }
        #undef BLK
    }
    __syncthreads();

    // ---- Phase 4: proj GEMM [64x192]@[192x192] + bias + residual ----
    {
        f32x4 a2[4][2];
        #pragma unroll
        for (int mi=0; mi<4; ++mi)
            #pragma unroll
            for (int ni=0; ni<2; ++ni) a2[mi][ni] = f32x4{0.f,0.f,0.f,0.f};
        #pragma unroll
        for (int ks=0; ks<6; ++ks) {
            bf16x8 af[4], bw[2];
            #pragma unroll
            for (int mi=0; mi<4; ++mi)
                af[mi] = ldfrag(&smem[(u32)((mi*6+ks)*512) + lsw*8]);
            #pragma unroll
            for (int ni=0; ni<2; ++ni)
                bw[ni] = ldfrag(&wproj_t[(wid*32 + 16*ni + lr)*192 + 32*ks + 8*lg]);
            #pragma unroll
            for (int mi=0; mi<4; ++mi)
                #pragma unroll
                for (int ni=0; ni<2; ++ni)
                    a2[mi][ni] = __builtin_amdgcn_mfma_f32_16x16x32_bf16(af[mi], bw[ni], a2[mi][ni], 0,0,0);
        }
        #pragma unroll
        for (int ni=0; ni<2; ++ni) {
            const int c  = wid*32 + 16*ni + lr;
            const float pb = proj_b[c];
            #pragma unroll
            for (int mi=0; mi<4; ++mi)
                #pragma unroll
                for (int rg=0; rg<4; ++rg) {
                    const int row = 16*mi + 4*lg + rg;
                    const int ty = row >> 3, tx = row & 7;
                    const int shy = (wy*8 + ty + SHIFT) & 127;
                    const int shx = (wx*8 + tx + SHIFT) & 127;
                    const size_t idx = ((size_t)((b*128 + shy)*128 + shx))*192 + c;
                    xout[idx] = xin[idx] + a2[mi][ni][rg] + pb;
                }
        }
    }
}

// ws layout (u16): [0) wqkv1_t 110592 | 110592) wproj1_t 36864 | 147456) wqkv2_t 110592 | 258048) wproj2_t 36864
__global__ void prep_weights(const float* __restrict__ qkv1, const float* __restrict__ proj1,
                             const float* __restrict__ qkv2, const float* __restrict__ proj2,
                             u16* __restrict__ ws)
{
    const int i = blockIdx.x*blockDim.x + threadIdx.x;
    if (i < 110592) {
        const int n = i / 192, k = i - n*192;
        ws[i]          = f2bf(qkv1[k*576 + n]);
        ws[147456 + i] = f2bf(qkv2[k*576 + n]);
    }
    if (i < 36864) {
        const int n = i / 192, k = i - n*192;
        ws[110592 + i] = f2bf(proj1[k*192 + n]);
        ws[258048 + i] = f2bf(proj2[k*192 + n]);
    }
}

extern "C" void kernel_launch(void* const* d_in, const int* in_sizes, int n_in,
                              void* d_out, int out_size, void* d_ws, size_t ws_size,
                              hipStream_t stream)
{
    const float* x       = (const float*)d_in[0];
    const float* ln1_g   = (const float*)d_in[1];
    const float* ln1_b   = (const float*)d_in[2];
    const float* qkv1_w  = (const float*)d_in[3];
    const float* qkv1_b  = (const float*)d_in[4];
    const float* proj1_w = (const float*)d_in[5];
    const float* proj1_b = (const float*)d_in[6];
    const float* ln2_g   = (const float*)d_in[7];
    const float* ln2_b   = (const float*)d_in[8];
    const float* qkv2_w  = (const float*)d_in[9];
    const float* qkv2_b  = (const float*)d_in[10];
    const float* proj2_w = (const float*)d_in[11];
    const float* proj2_b = (const float*)d_in[12];
    float* out = (float*)d_out;
    u16*   wsp = (u16*)d_ws;

    prep_weights<<<dim3(432), dim3(256), 0, stream>>>(qkv1_w, proj1_w, qkv2_w, proj2_w, wsp);
    swin_branch<0><<<dim3(2048), dim3(384), 0, stream>>>(x,   out, ln1_g, ln1_b,
                                                         wsp,        qkv1_b, wsp+110592, proj1_b);
    swin_branch<4><<<dim3(2048), dim3(384), 0, stream>>>(out, out, ln2_g, ln2_b,
                                                         wsp+147456, qkv2_b, wsp+258048, proj2_b);
}

// Round 7
// 297.387 us; speedup vs baseline: 1.1828x; 1.1828x over previous
//
#include <hip/hip_runtime.h>

typedef unsigned int   u32;
typedef unsigned short u16;
typedef __bf16 bf16x8 __attribute__((ext_vector_type(8)));
typedef float  f32x4  __attribute__((ext_vector_type(4)));

__device__ __forceinline__ u16 f2bf(float f) {
    u32 u = __builtin_bit_cast(u32, f);
    u += 0x7FFFu + ((u >> 16) & 1u);
    return (u16)(u >> 16);
}
__device__ __forceinline__ u32 pk2bf(float a, float b) {
    return (u32)f2bf(a) | ((u32)f2bf(b) << 16);
}
__device__ __forceinline__ bf16x8 ldfrag(const u16* p) {
    return __builtin_bit_cast(bf16x8, *reinterpret_cast<const uint4*>(p));
}

// bank-conflict swizzle on the 16B-chunk index (0..63): fold bits[5:3] into [2:0].
__device__ __forceinline__ u32 swz(u32 i) { return i ^ ((i >> 3) & 7u); }

// ---------------------------------------------------------------------------
// Fused Swin branch: LN -> QKV -> windowed MHA -> proj -> +residual
// WG = 768 threads = 12 waves = TWO independent 8x8 windows (6 waves each,
// wave == head). 12-wave WGs place 3 waves on each SIMD (balanced), unlike
// 6-wave WGs whose 2,2,1,1 placement blocks a 2nd WG at our ~140-reg/wave
// footprint (R1-R6 evidence: occupancy pinned at 6 waves/CU regardless of
// LDS 28..118KB). One WG/CU = 12 waves = 2x TLP.
// Per-window LDS partition (u16, base = win*24576):
//   [0,12288)      yln: 24 frag blocks (mi*6+ks)*512 + swz(pos)*8 + j.
//                  Phase 3: wave w's own blocks {s*6+w} = scratch for
//                  k -> V^T -> attn_out (serial, wave-local, DS in-order).
//   [12288,24576)  qreg: per-head q A-frags; P staging reuses it after QK^T.
// k,v cross the QKV barrier packed in registers (kpk/vpk).
// ---------------------------------------------------------------------------
template<int SHIFT>
__global__ __launch_bounds__(768) void swin_branch(
    const float* __restrict__ xin, float* __restrict__ xout,
    const float* __restrict__ ln_g, const float* __restrict__ ln_b,
    const u16*   __restrict__ wqkv_t,  // [576][192] bf16 (pre-transposed)
    const float* __restrict__ qkv_b,   // [576]
    const u16*   __restrict__ wproj_t, // [192][192] bf16 (pre-transposed)
    const float* __restrict__ proj_b)  // [192]
{
    __shared__ __align__(16) u16 smem[49152];
    __shared__ float red1[2][6][64];
    __shared__ float red2[2][6][64];
    constexpr u32 QOFF = 12288;

    const int tid  = threadIdx.x;
    const int win  = (tid >= 384) ? 1 : 0;  // which of the WG's two windows
    const int lt   = tid - win*384;
    const int wid  = lt >> 6;               // wave == head
    const int lane = lt & 63;
    const int lr   = lane & 15;
    const int lg   = lane >> 4;
    const u32 lsw  = swz((u32)lane);        // read-side chunk index
    const u32 SB   = (u32)win * 24576u;     // per-window LDS base

    const int Wid = blockIdx.x*2 + win;     // b*256 + wy*16 + wx
    const int b   = Wid >> 8;
    const int wy  = (Wid >> 4) & 15;
    const int wx  = Wid & 15;

    // ---- Phase 1: gather window (rolled), LayerNorm -> yln (A-frag layout) ----
    {
        const int ty = lane >> 3, tx = lane & 7;
        const int shy = (wy*8 + ty + SHIFT) & 127;
        const int shx = (wx*8 + tx + SHIFT) & 127;
        const float* xp = xin + ((size_t)((b*128 + shy)*128 + shx))*192 + wid*32;
        float xv[32];
        float s1 = 0.f, s2 = 0.f;
        #pragma unroll
        for (int j = 0; j < 8; ++j) {
            float4 v = reinterpret_cast<const float4*>(xp)[j];
            xv[j*4+0]=v.x; xv[j*4+1]=v.y; xv[j*4+2]=v.z; xv[j*4+3]=v.w;
            s1 += v.x+v.y+v.z+v.w;
            s2 += v.x*v.x + v.y*v.y + v.z*v.z + v.w*v.w;
        }
        red1[win][wid][lane] = s1; red2[win][wid][lane] = s2;
        __syncthreads();
        float a1 = 0.f, a2 = 0.f;
        #pragma unroll
        for (int w = 0; w < 6; ++w) { a1 += red1[win][w][lane]; a2 += red2[win][w][lane]; }
        const float mu = a1 * (1.f/192.f);
        const float rs = rsqrtf(a2 * (1.f/192.f) - mu*mu + 1e-5f);
        const float* gp = ln_g + wid*32;
        const float* bp = ln_b + wid*32;
        const u32 yblk = SB + (u32)((lg*6 + wid)*512);
        #pragma unroll
        for (int cc8 = 0; cc8 < 4; ++cc8) {
            u32 pk[4];
            #pragma unroll
            for (int q = 0; q < 4; ++q) {
                int j = cc8*8 + q*2;
                float y0 = (xv[j]   - mu)*rs*gp[j]   + bp[j];
                float y1 = (xv[j+1] - mu)*rs*gp[j+1] + bp[j+1];
                pk[q] = pk2bf(y0, y1);
            }
            *reinterpret_cast<uint4*>(&smem[yblk + swz((u32)(lr + 16*cc8))*8]) =
                make_uint4(pk[0],pk[1],pk[2],pk[3]);
        }
    }
    __syncthreads();

    // ---- Phase 2: QKV GEMM, two passes to cap accumulator liveness ----
    uint2 kpk[4][2];     // k packed bf16 (crosses barrier in regs)
    uint2 vpk[4][2];     // v packed bf16 (crosses barrier in regs)
    {
        // pass 1: q,k (16 accumulators); q -> qreg (wave-private LDS, pre-barrier)
        {
            f32x4 acc[4][4];
            #pragma unroll
            for (int mi=0; mi<4; ++mi)
                #pragma unroll
                for (int t=0; t<4; ++t) acc[mi][t] = f32x4{0.f,0.f,0.f,0.f};
            #pragma unroll
            for (int ks=0; ks<6; ++ks) {
                bf16x8 af[4];
                #pragma unroll
                for (int mi=0; mi<4; ++mi)
                    af[mi] = ldfrag(&smem[SB + (u32)((mi*6+ks)*512) + lsw*8]);
                bf16x8 bw[4];
                #pragma unroll
                for (int t=0; t<4; ++t)
                    bw[t] = ldfrag(&wqkv_t[((t>>1)*192 + wid*32 + (t&1)*16 + lr)*192 + 32*ks + 8*lg]);
                #pragma unroll
                for (int mi=0; mi<4; ++mi)
                    #pragma unroll
                    for (int t=0; t<4; ++t)
                        acc[mi][t] = __builtin_amdgcn_mfma_f32_16x16x32_bf16(af[mi], bw[t], acc[mi][t], 0,0,0);
            }
            // q: bias+scale, scatter to qreg; k: bias, pack to regs
            #pragma unroll
            for (int t=0; t<2; ++t) {
                const float bias = qkv_b[wid*32 + t*16 + lr];
                const u32 lphi   = (u32)(16*(2*t + (lr>>3)));
                #pragma unroll
                for (int mi=0; mi<4; ++mi)
                    #pragma unroll
                    for (int rg=0; rg<4; ++rg) {
                        const u32 pos = (u32)(4*lg + rg) + lphi;
                        smem[SB + QOFF + (u32)(wid*2048) + mi*512 + swz(pos)*8 + (lr&7)] =
                            f2bf((acc[mi][t][rg] + bias) * 0.1767766952966369f);
                    }
            }
            #pragma unroll
            for (int t2=0; t2<2; ++t2) {
                const float bias = qkv_b[192 + wid*32 + t2*16 + lr];
                #pragma unroll
                for (int mi=0; mi<4; ++mi)
                    kpk[mi][t2] = make_uint2(
                        pk2bf(acc[mi][2+t2][0] + bias, acc[mi][2+t2][1] + bias),
                        pk2bf(acc[mi][2+t2][2] + bias, acc[mi][2+t2][3] + bias));
            }
        }
        // pass 2: v (8 accumulators), pack to bf16 pairs
        {
            f32x4 vacc[4][2];
            #pragma unroll
            for (int mi=0; mi<4; ++mi)
                #pragma unroll
                for (int t=0; t<2; ++t) vacc[mi][t] = f32x4{0.f,0.f,0.f,0.f};
            #pragma unroll
            for (int ks=0; ks<6; ++ks) {
                bf16x8 af[4];
                #pragma unroll
                for (int mi=0; mi<4; ++mi)
                    af[mi] = ldfrag(&smem[SB + (u32)((mi*6+ks)*512) + lsw*8]);
                bf16x8 bw[2];
                #pragma unroll
                for (int t=0; t<2; ++t)
                    bw[t] = ldfrag(&wqkv_t[(384 + wid*32 + t*16 + lr)*192 + 32*ks + 8*lg]);
                #pragma unroll
                for (int mi=0; mi<4; ++mi)
                    #pragma unroll
                    for (int t=0; t<2; ++t)
                        vacc[mi][t] = __builtin_amdgcn_mfma_f32_16x16x32_bf16(af[mi], bw[t], vacc[mi][t], 0,0,0);
            }
            #pragma unroll
            for (int tv=0; tv<2; ++tv) {
                const float bias = qkv_b[384 + wid*32 + tv*16 + lr];
                #pragma unroll
                for (int mi=0; mi<4; ++mi)
                    vpk[mi][tv] = make_uint2(
                        pk2bf(vacc[mi][tv][0] + bias, vacc[mi][tv][1] + bias),
                        pk2bf(vacc[mi][tv][2] + bias, vacc[mi][tv][3] + bias));
            }
        }
    }
    __syncthreads();   // yln reads done -> wave w's blocks {s*6+w} become scratch

    // ---- Phase 3: attention, fully wave-local ----
    float rsum[4][4];
    f32x4 o_[4][2];
    {
        const u32 W  = SB + (u32)(wid*512);
        const u32 qb = SB + QOFF + (u32)(wid*2048);
        #define BLK(s) ((u32)(s)*3072u + W)

        // k scatter (from kpk) -> scratch blocks, read B-frags
        #pragma unroll
        for (int t2=0; t2<2; ++t2) {
            const u32 lphi = (u32)(16*(2*t2 + (lr>>3)));
            #pragma unroll
            for (int mi=0; mi<4; ++mi) {
                const u32 a0 = BLK(mi) + (lr&7);
                smem[a0 + swz((u32)(4*lg+0) + lphi)*8] = (u16)(kpk[mi][t2].x);
                smem[a0 + swz((u32)(4*lg+1) + lphi)*8] = (u16)(kpk[mi][t2].x >> 16);
                smem[a0 + swz((u32)(4*lg+2) + lphi)*8] = (u16)(kpk[mi][t2].y);
                smem[a0 + swz((u32)(4*lg+3) + lphi)*8] = (u16)(kpk[mi][t2].y >> 16);
            }
        }
        bf16x8 aq[4], bk[4];
        #pragma unroll
        for (int mi=0; mi<4; ++mi) aq[mi] = ldfrag(&smem[qb + mi*512 + lsw*8]);
        #pragma unroll
        for (int ni=0; ni<4; ++ni) bk[ni] = ldfrag(&smem[BLK(ni) + lsw*8]);
        __builtin_amdgcn_sched_barrier(0);

        // V^T scatter into same scratch (k dead after bk reads; DS in-order)
        #pragma unroll
        for (int tv=0; tv<2; ++tv)
            #pragma unroll
            for (int mi=0; mi<4; ++mi) {
                const u32 pos = (u32)(lr + 16*(2*(mi&1) + (lg>>1)));
                *reinterpret_cast<uint2*>(
                    &smem[BLK(tv*2 + (mi>>1)) + swz(pos)*8 + 4*(lg&1)]) = vpk[mi][tv];
            }

        f32x4 s[4][4];
        #pragma unroll
        for (int mi=0; mi<4; ++mi)
            #pragma unroll
            for (int ni=0; ni<4; ++ni)
                s[mi][ni] = __builtin_amdgcn_mfma_f32_16x16x32_bf16(aq[mi], bk[ni],
                                f32x4{0.f,0.f,0.f,0.f}, 0,0,0);

        if constexpr (SHIFT > 0) {
            int kl[4];
            #pragma unroll
            for (int ni=0; ni<4; ++ni) {
                const int col = 16*ni + lr;
                const int hu = wy*8 + (col>>3);
                const int wu = wx*8 + (col&7);
                kl[ni] = ((hu >= 124) ? 2 : (hu >= 120 ? 1 : 0))*3
                       + ((wu >= 124) ? 2 : (wu >= 120 ? 1 : 0));
            }
            #pragma unroll
            for (int mi=0; mi<4; ++mi)
                #pragma unroll
                for (int rg=0; rg<4; ++rg) {
                    const int row = 16*mi + 4*lg + rg;
                    const int hu = wy*8 + (row>>3);
                    const int wu = wx*8 + (row&7);
                    const int rl = ((hu >= 124) ? 2 : (hu >= 120 ? 1 : 0))*3
                                 + ((wu >= 124) ? 2 : (wu >= 120 ? 1 : 0));
                    #pragma unroll
                    for (int ni=0; ni<4; ++ni)
                        if (rl != kl[ni]) s[mi][ni][rg] += -100.f;
                }
        }

        // row softmax in registers (row's 64 cols = 16 lanes x 4 ni)
        #pragma unroll
        for (int mi=0; mi<4; ++mi)
            #pragma unroll
            for (int rg=0; rg<4; ++rg) {
                float m = fmaxf(fmaxf(s[mi][0][rg], s[mi][1][rg]), fmaxf(s[mi][2][rg], s[mi][3][rg]));
                #pragma unroll
                for (int off=1; off<16; off<<=1) m = fmaxf(m, __shfl_xor(m, off, 64));
                float sm = 0.f;
                #pragma unroll
                for (int ni=0; ni<4; ++ni) {
                    float e = __expf(s[mi][ni][rg] - m);
                    s[mi][ni][rg] = e;
                    sm += e;
                }
                #pragma unroll
                for (int off=1; off<16; off<<=1) sm += __shfl_xor(sm, off, 64);
                rsum[mi][rg] = 1.0f / sm;
            }

        // P staged in two ksv halves in qreg (q dead after QK^T); frags to regs
        bf16x8 ap0[4], ap1[4];
        #pragma unroll
        for (int mi=0; mi<4; ++mi)
            #pragma unroll
            for (int ni=0; ni<2; ++ni)
                #pragma unroll
                for (int rg=0; rg<4; ++rg) {
                    const u32 pos = (u32)(4*lg + rg + 16*(2*ni + (lr>>3)));
                    smem[qb + mi*512 + swz(pos)*8 + (lr&7)] = f2bf(s[mi][ni][rg]);
                }
        #pragma unroll
        for (int mi=0; mi<4; ++mi) ap0[mi] = ldfrag(&smem[qb + mi*512 + lsw*8]);
        __builtin_amdgcn_sched_barrier(0);
        #pragma unroll
        for (int mi=0; mi<4; ++mi)
            #pragma unroll
            for (int ni=2; ni<4; ++ni)
                #pragma unroll
                for (int rg=0; rg<4; ++rg) {
                    const u32 pos = (u32)(4*lg + rg + 16*(2*(ni-2) + (lr>>3)));
                    smem[qb + mi*512 + swz(pos)*8 + (lr&7)] = f2bf(s[mi][ni][rg]);
                }
        #pragma unroll
        for (int mi=0; mi<4; ++mi) ap1[mi] = ldfrag(&smem[qb + mi*512 + lsw*8]);
        __builtin_amdgcn_sched_barrier(0);

        bf16x8 bv[2][2];
        #pragma unroll
        for (int tv=0; tv<2; ++tv)
            #pragma unroll
            for (int ksv=0; ksv<2; ++ksv)
                bv[tv][ksv] = ldfrag(&smem[BLK(tv*2+ksv) + lsw*8]);

        // PV
        #pragma unroll
        for (int mi=0; mi<4; ++mi)
            #pragma unroll
            for (int tv=0; tv<2; ++tv) {
                o_[mi][tv] = __builtin_amdgcn_mfma_f32_16x16x32_bf16(ap0[mi], bv[tv][0],
                                 f32x4{0.f,0.f,0.f,0.f}, 0,0,0);
                o_[mi][tv] = __builtin_amdgcn_mfma_f32_16x16x32_bf16(ap1[mi], bv[tv][1],
                                 o_[mi][tv], 0,0,0);
            }
        __builtin_amdgcn_sched_barrier(0);

        // normalized attn_out -> own scratch blocks (= proj A-frag blocks ks=wid)
        #pragma unroll
        for (int mi=0; mi<4; ++mi)
            #pragma unroll
            for (int tv=0; tv<2; ++tv)
                #pragma unroll
                for (int rg=0; rg<4; ++rg) {
                    const u32 pos = (u32)(4*lg + rg + 16*(2*tv + (lr>>3)));
                    smem[BLK(mi) + swz(pos)*8 + (lr&7)] = f2bf(o_[mi][tv][rg] * rsum[mi][rg]);
                }
        #undef BLK
    }
    __syncthreads();

    // ---- Phase 4: proj GEMM [64x192]@[192x192] + bias + residual ----
    {
        f32x4 a2[4][2];
        #pragma unroll
        for (int mi=0; mi<4; ++mi)
            #pragma unroll
            for (int ni=0; ni<2; ++ni) a2[mi][ni] = f32x4{0.f,0.f,0.f,0.f};
        #pragma unroll
        for (int ks=0; ks<6; ++ks) {
            bf16x8 af[4], bw[2];
            #pragma unroll
            for (int mi=0; mi<4; ++mi)
                af[mi] = ldfrag(&smem[SB + (u32)((mi*6+ks)*512) + lsw*8]);
            #pragma unroll
            for (int ni=0; ni<2; ++ni)
                bw[ni] = ldfrag(&wproj_t[(wid*32 + 16*ni + lr)*192 + 32*ks + 8*lg]);
            #pragma unroll
            for (int mi=0; mi<4; ++mi)
                #pragma unroll
                for (int ni=0; ni<2; ++ni)
                    a2[mi][ni] = __builtin_amdgcn_mfma_f32_16x16x32_bf16(af[mi], bw[ni], a2[mi][ni], 0,0,0);
        }
        #pragma unroll
        for (int ni=0; ni<2; ++ni) {
            const int c  = wid*32 + 16*ni + lr;
            const float pb = proj_b[c];
            #pragma unroll
            for (int mi=0; mi<4; ++mi)
                #pragma unroll
                for (int rg=0; rg<4; ++rg) {
                    const int row = 16*mi + 4*lg + rg;
                    const int ty = row >> 3, tx = row & 7;
                    const int shy = (wy*8 + ty + SHIFT) & 127;
                    const int shx = (wx*8 + tx + SHIFT) & 127;
                    const size_t idx = ((size_t)((b*128 + shy)*128 + shx))*192 + c;
                    xout[idx] = xin[idx] + a2[mi][ni][rg] + pb;
                }
        }
    }
}

// ws layout (u16): [0) wqkv1_t 110592 | 110592) wproj1_t 36864 | 147456) wqkv2_t 110592 | 258048) wproj2_t 36864
__global__ void prep_weights(const float* __restrict__ qkv1, const float* __restrict__ proj1,
                             const float* __restrict__ qkv2, const float* __restrict__ proj2,
                             u16* __restrict__ ws)
{
    const int i = blockIdx.x*blockDim.x + threadIdx.x;
    if (i < 110592) {
        const int n = i / 192, k = i - n*192;
        ws[i]          = f2bf(qkv1[k*576 + n]);
        ws[147456 + i] = f2bf(qkv2[k*576 + n]);
    }
    if (i < 36864) {
        const int n = i / 192, k = i - n*192;
        ws[110592 + i] = f2bf(proj1[k*192 + n]);
        ws[258048 + i] = f2bf(proj2[k*192 + n]);
    }
}

extern "C" void kernel_launch(void* const* d_in, const int* in_sizes, int n_in,
                              void* d_out, int out_size, void* d_ws, size_t ws_size,
                              hipStream_t stream)
{
    const float* x       = (const float*)d_in[0];
    const float* ln1_g   = (const float*)d_in[1];
    const float* ln1_b   = (const float*)d_in[2];
    const float* qkv1_w  = (const float*)d_in[3];
    const float* qkv1_b  = (const float*)d_in[4];
    const float* proj1_w = (const float*)d_in[5];
    const float* proj1_b = (const float*)d_in[6];
    const float* ln2_g   = (const float*)d_in[7];
    const float* ln2_b   = (const float*)d_in[8];
    const float* qkv2_w  = (const float*)d_in[9];
    const float* qkv2_b  = (const float*)d_in[10];
    const float* proj2_w = (const float*)d_in[11];
    const float* proj2_b = (const float*)d_in[12];
    float* out = (float*)d_out;
    u16*   wsp = (u16*)d_ws;

    prep_weights<<<dim3(432), dim3(256), 0, stream>>>(qkv1_w, proj1_w, qkv2_w, proj2_w, wsp);
    swin_branch<0><<<dim3(1024), dim3(768), 0, stream>>>(x,   out, ln1_g, ln1_b,
                                                         wsp,        qkv1_b, wsp+110592, proj1_b);
    swin_branch<4><<<dim3(1024), dim3(768), 0, stream>>>(out, out, ln2_g, ln2_b,
                                                         wsp+147456, qkv2_b, wsp+258048, proj2_b);
}